// Round 10
// baseline (320.776 us; speedup 1.0000x reference)
//
#include <hip/hip_runtime.h>
#include <math.h>

#define D      256
#define BI     256     // rows per block (16 m-tiles of 16; 4 mg-waves x 4 mt each)
#define NTHR   512     // 8 waves: mg = wv&3, jg = wv>>2
#define KL     3       // per-stream top-k
#define NC     6       // refine candidates per row per quarter
#define STILE  64      // j per supertile (4 subtiles of 16) = 32 KB fp16
#define BUFH   16384   // halfs per stage buffer (32 KB); 3 buffers = 96 KB

typedef _Float16 half8 __attribute__((ext_vector_type(8)));
typedef float f32x4 __attribute__((ext_vector_type(4)));
typedef __attribute__((address_space(3))) unsigned int lds_u32;
typedef const __attribute__((address_space(1))) unsigned int glb_u32;

// s_waitcnt simm16 (gfx9/CDNA): vmcnt[3:0] | expcnt<<4 | lgkmcnt<<8 | vmcnt[5:4]<<14
#define WAITCNT_VM4  0xF74   // vmcnt(4): my 4 newest (next-tile) loads may remain
#define WAITCNT_VM0  0xF70   // vmcnt(0)

#if __has_builtin(__builtin_amdgcn_sched_barrier)
#define SCHED_FENCE() __builtin_amdgcn_sched_barrier(0)
#else
#define SCHED_FENCE()
#endif

// ---- fused prep (R9-proven): per-row fp64 norm + invn + fp16 pack (tile order) ----
__global__ __launch_bounds__(256) void prep_kernel(const float* __restrict__ x,
    double* __restrict__ fen64, float* __restrict__ invn,
    _Float16* __restrict__ xBs, float* __restrict__ g, int n) {
  const int T   = blockIdx.x;          // one 16-row tile
  const int tid = threadIdx.x;
  const int r   = tid >> 4;
  const int t   = tid & 15;
  const int row = T * 16 + r;
  if (T == 0) g[tid] = 0.f;

  float4 v[4];
  const float* sp = x + (size_t)row * D + t * 16;
  #pragma unroll
  for (int q = 0; q < 4; ++q) v[q] = *reinterpret_cast<const float4*>(sp + q * 4);

  double s = 0.0;
  #pragma unroll
  for (int q = 0; q < 4; ++q)
    s += (double)v[q].x * v[q].x + (double)v[q].y * v[q].y +
         (double)v[q].z * v[q].z + (double)v[q].w * v[q].w;
  s += __shfl_down(s, 8); s += __shfl_down(s, 4);
  s += __shfl_down(s, 2); s += __shfl_down(s, 1);

  __shared__ float sInv[16];
  if (t == 0) {
    const double f = sqrt(s + D * 1e-6);   // ref adds 1e-6 per element before summing
    fen64[row] = f;
    const float iv = (float)(1.0 / f);
    invn[row] = iv;
    sInv[r] = iv;
  }
  __syncthreads();
  const float inv = sInv[r];

  const int kc  = t >> 1;
  const int hi0 = (t & 1) * 2;
  half8 h0, h1;
  h0[0] = (_Float16)(v[0].x * inv); h0[1] = (_Float16)(v[0].y * inv);
  h0[2] = (_Float16)(v[0].z * inv); h0[3] = (_Float16)(v[0].w * inv);
  h0[4] = (_Float16)(v[1].x * inv); h0[5] = (_Float16)(v[1].y * inv);
  h0[6] = (_Float16)(v[1].z * inv); h0[7] = (_Float16)(v[1].w * inv);
  h1[0] = (_Float16)(v[2].x * inv); h1[1] = (_Float16)(v[2].y * inv);
  h1[2] = (_Float16)(v[2].z * inv); h1[3] = (_Float16)(v[2].w * inv);
  h1[4] = (_Float16)(v[3].x * inv); h1[5] = (_Float16)(v[3].y * inv);
  h1[6] = (_Float16)(v[3].z * inv); h1[7] = (_Float16)(v[3].w * inv);
  _Float16* base = xBs + (size_t)T * 4096;
  *reinterpret_cast<half8*>(base + kc * 512 + (hi0 * 16 + r) * 8) = h0;
  *reinterpret_cast<half8*>(base + kc * 512 + ((hi0 + 1) * 16 + r) * 8) = h1;
}

// ---- g[d] = sum_i x[i][d]*invn[i]  (Z series input; ~1% tolerance) ----
__global__ __launch_bounds__(256) void gsum_kernel(const float* __restrict__ x,
    const float* __restrict__ invn, float* __restrict__ g) {
  const int d = threadIdx.x;
  const int r0 = blockIdx.x * 256;
  float acc = 0.f;
  for (int r = 0; r < 256; ++r)
    acc += x[(size_t)(r0 + r) * D + d] * invn[r0 + r];
  atomicAdd(&g[d], acc);
}

__device__ inline void ins6(unsigned int v, unsigned int* b) {
  if (v > b[5]) {
    bool g0 = v > b[0], g1 = v > b[1], g2 = v > b[2], g3 = v > b[3], g4 = v > b[4];
    unsigned int o0 = b[0], o1 = b[1], o2 = b[2], o3 = b[3], o4 = b[4];
    b[5] = g4 ? o4 : v;             b[4] = g4 ? (g3 ? o3 : v) : o4;
    b[3] = g3 ? (g2 ? o2 : v) : o3; b[2] = g2 ? (g1 ? o1 : v) : o2;
    b[1] = g1 ? (g0 ? o0 : v) : o1; b[0] = g0 ? v : o0;
  }
}

// ---- main: BI=256 x j-quarter; 4 m-tiles/wave (1 B-read -> 4 MFMA); float top-3 ----
__global__ __launch_bounds__(NTHR, 2) void neighbors_kernel(
    const _Float16* __restrict__ xBs, unsigned int* __restrict__ cand6, int n) {
  extern __shared__ char smem[];
  _Float16* sB = (_Float16*)smem;                   // 3 x BUFH halfs (96 KB)
  unsigned int* cand = (unsigned int*)smem;         // [BI][96] aliases stage (96 KB)
  const int tid  = threadIdx.x;
  const int lane = tid & 63;
  const int wv   = tid >> 6;
  const int mg   = wv & 3;    // m-wave-group: 4 m-tiles of 16 (64 rows)
  const int jg   = wv >> 2;   // 2 j-subtiles (of 4) within 64-j supertile
  const int nIdx = lane & 15;
  const int quad = lane >> 4;
  const int ib   = blockIdx.x >> 2;
  const int q    = blockIdx.x & 3;      // j-quarter
  const int i0   = ib * BI;
  const int nq   = n >> 2;              // 4096 j per quarter
  const int NST  = nq / STILE;          // 64 supertiles per quarter
  const int tb   = q * (nq / 16);       // first 16-j tile index of this quarter

  // A fragments: 4 m-tiles x 8 k-chunks, NEGATED (acc=1-cos), layout == B-frags
  half8 afrag[4][8];
  #pragma unroll
  for (int mt = 0; mt < 4; ++mt) {
    const _Float16* ap = xBs + (size_t)(i0 / 16 + mg * 4 + mt) * 4096 + lane * 8;
    #pragma unroll
    for (int kc = 0; kc < 8; ++kc) {
      half8 a = *reinterpret_cast<const half8*>(ap + kc * 512);
      afrag[mt][kc] = -a;
    }
  }

  // per-lane top-3 (float keys: smaller = better; value|j packed, j ties -> lower j)
  float tkv[16][KL];
  #pragma unroll
  for (int e = 0; e < 16; ++e)
    #pragma unroll
    for (int c = 0; c < KL; ++c) tkv[e][c] = __builtin_inff();

  const int jbase = q * 4096 + jg * 32 + nIdx;   // + jt*64 + js*16 at use (disjoint bits)

  // DMA: supertile = 32 KB contiguous in xBs; wave copies its 4 KB (4 x 1 KB)
  auto dma_tile = [&](int st, int bufI) {
    const _Float16* src = xBs + ((size_t)tb + st * 4) * 4096 + wv * 2048 + lane * 8;
    _Float16* dst = sB + (size_t)bufI * BUFH + wv * 2048;
    #pragma unroll
    for (int c = 0; c < 4; ++c)
      __builtin_amdgcn_global_load_lds((glb_u32*)(src + c * 512),
                                       (lds_u32*)(dst + c * 512), 16, 0, 0);
  };

  auto compute = [&](int jt) {
    const int b = jt % 3;
    const _Float16* bbase = sB + (size_t)b * BUFH + (jg * 2) * 4096 + lane * 8;
    #pragma unroll
    for (int js = 0; js < 2; ++js) {
      f32x4 acc[4];
      #pragma unroll
      for (int mt = 0; mt < 4; ++mt) acc[mt] = f32x4{1.f, 1.f, 1.f, 1.f};
      const _Float16* bb = bbase + js * 4096;
      #pragma unroll
      for (int kc = 0; kc < 8; ++kc) {
        const half8 bf = *reinterpret_cast<const half8*>(bb + kc * 512);
        acc[0] = __builtin_amdgcn_mfma_f32_16x16x32_f16(afrag[0][kc], bf, acc[0], 0, 0, 0);
        acc[1] = __builtin_amdgcn_mfma_f32_16x16x32_f16(afrag[1][kc], bf, acc[1], 0, 0, 0);
        acc[2] = __builtin_amdgcn_mfma_f32_16x16x32_f16(afrag[2][kc], bf, acc[2], 0, 0, 0);
        acc[3] = __builtin_amdgcn_mfma_f32_16x16x32_f16(afrag[3][kc], bf, acc[3], 0, 0, 0);
      }
      const int jv = jbase + jt * 64 + js * 16;
      #pragma unroll
      for (int mt = 0; mt < 4; ++mt) {
        #pragma unroll
        for (int r = 0; r < 4; ++r) {
          const float s = acc[mt][r];    // = 1 - cos  (>=0; self may be tiny negative)
          const unsigned int pu = (__float_as_uint(s) & 0xFFFFC000u) | (unsigned int)jv;
          const float p = __uint_as_float(pu);
          const int e = mt * 4 + r;
          const float t0 = tkv[e][0], t1 = tkv[e][1], t2 = tkv[e][2];
          // exact sorted-ascending top-3 insert in 3 ops (min + 2x med3)
          tkv[e][0] = fminf(t0, p);
          tkv[e][1] = __builtin_amdgcn_fmed3f(t0, t1, p);
          tkv[e][2] = __builtin_amdgcn_fmed3f(t1, t2, p);
        }
      }
    }
  };

  dma_tile(0, 0);
  dma_tile(1, 1);
  for (int jt = 0; jt < NST - 1; ++jt) {
    __builtin_amdgcn_s_waitcnt(WAITCNT_VM4);   // my 4 loads for buf jt landed
    __builtin_amdgcn_s_barrier();              // all waves' buf-jt loads landed
    SCHED_FENCE();
    if (jt + 2 < NST) dma_tile(jt + 2, (jt + 2) % 3);
    compute(jt);
  }
  __builtin_amdgcn_s_waitcnt(WAITCNT_VM0);
  __builtin_amdgcn_s_barrier();
  SCHED_FENCE();
  compute(NST - 1);

  __syncthreads();   // stage dead; switch to merge layout

  // deposit: float key -> monotone-descending u32 (best = largest, for ins6-max)
  #pragma unroll
  for (int mt = 0; mt < 4; ++mt) {
    #pragma unroll
    for (int r = 0; r < 4; ++r) {
      const int row  = (mg * 4 + mt) * 16 + quad * 4 + r;
      const int slot = jg * 16 + nIdx;
      #pragma unroll
      for (int c = 0; c < KL; ++c) {
        const unsigned int u = __float_as_uint(tkv[mt * 4 + r][c]);
        const unsigned int m = ((int)u < 0) ? ~u : (u + 0x80000000u);
        cand[row * 96 + slot * KL + c] = ~m;
      }
    }
  }
  __syncthreads();

  // stage-A: 2 threads/row, each reduces 48 candidates to top-6 in place
  {
    const int row = tid >> 1, seg = tid & 1, base = seg * 48;
    unsigned int best[NC];
    #pragma unroll
    for (int c = 0; c < NC; ++c) best[c] = 0u;
    for (int k = 0; k < 48; ++k) ins6(cand[row * 96 + base + k], best);
    #pragma unroll
    for (int c = 0; c < NC; ++c) cand[row * 96 + base + c] = best[c];
  }
  __syncthreads();

  // stage-B: one thread/row -> top-6 keys to global scratch [i][4 quarters][6]
  if (tid < BI) {
    unsigned int best[NC];
    #pragma unroll
    for (int c = 0; c < NC; ++c) best[c] = 0u;
    for (int seg = 0; seg < 2; ++seg)
      for (int c = 0; c < NC; ++c) ins6(cand[tid * 96 + seg * 48 + c], best);
    unsigned int* outp = cand6 + ((size_t)(i0 + tid) * 4 + q) * NC;
    #pragma unroll
    for (int c = 0; c < NC; ++c) outp[c] = best[c];
  }
}

// ---- finalize: merge 4 quarters, fp64 refine, Z series, weights, gather ----
__global__ __launch_bounds__(512) void finalize_kernel(
    const float* __restrict__ x, const unsigned int* __restrict__ cand6,
    const double* __restrict__ fen64, const float* __restrict__ invn,
    const float* __restrict__ g, float* __restrict__ out, int n) {
  __shared__ int    sel[32][NC];
  __shared__ double s64[32][NC];
  __shared__ float  psum[32][8];
  __shared__ float  wOut[32][3];
  __shared__ int    iOut[32][3];
  const int tid = threadIdx.x;
  const int base = blockIdx.x * 32;

  if (tid < 32) {                       // merge 24 keys -> top-6, decode j
    const unsigned int* cp = cand6 + (size_t)(base + tid) * 24;
    unsigned int best[NC];
    #pragma unroll
    for (int c = 0; c < NC; ++c) best[c] = 0u;
    for (int k = 0; k < 24; ++k) ins6(cp[k], best);
    #pragma unroll
    for (int c = 0; c < NC; ++c) {
      const unsigned int m = ~best[c];
      const unsigned int u = (m & 0x80000000u) ? (m & 0x7FFFFFFFu) : ~m;
      sel[tid][c] = (int)(u & 0x3FFFu);
    }
  }
  if (tid < 256) {                      // C1 partials: 8 threads/row x 32 d
    const int r = tid >> 3, seg = tid & 7;
    const float* xi = x + (size_t)(base + r) * D + seg * 32;
    const float* gp = g + seg * 32;
    float a = 0.f;
    #pragma unroll
    for (int d = 0; d < 32; d += 4) {
      float4 va = *reinterpret_cast<const float4*>(xi + d);
      float4 vg = *reinterpret_cast<const float4*>(gp + d);
      a += va.x * vg.x + va.y * vg.y + va.z * vg.z + va.w * vg.w;
    }
    psum[r][seg] = a;
  }
  __syncthreads();

  if (tid < 32 * NC) {                  // fp64 refine (numpy-order anchor)
    const int r = tid / NC, c = tid % NC;
    const int j = sel[r][c];
    const float* xi = x + (size_t)(base + r) * D;
    const float* xj = x + (size_t)j * D;
    double a0 = 0, a1 = 0, a2 = 0, a3 = 0;
    for (int d = 0; d < D; d += 4) {
      float4 va = *reinterpret_cast<const float4*>(xi + d);
      float4 vb = *reinterpret_cast<const float4*>(xj + d);
      a0 += (double)va.x * vb.x; a1 += (double)va.y * vb.y;
      a2 += (double)va.z * vb.z; a3 += (double)va.w * vb.w;
    }
    s64[r][c] = ((a0 + a1) + (a2 + a3)) / (fen64[base + r] * fen64[j]);
  }
  __syncthreads();

  if (tid < 32) {
    double sv0 = s64[tid][0], sv1 = s64[tid][1], sv2 = s64[tid][2],
           sv3 = s64[tid][3], sv4 = s64[tid][4], sv5 = s64[tid][5];
    int si0 = sel[tid][0], si1 = sel[tid][1], si2 = sel[tid][2],
        si3 = sel[tid][3], si4 = sel[tid][4], si5 = sel[tid][5];
#define CSW(a, b) { bool t_ = (sv##b > sv##a) || (sv##b == sv##a && si##b < si##a); \
    double d_ = t_ ? sv##b : sv##a; double e_ = t_ ? sv##a : sv##b; sv##a = d_; sv##b = e_; \
    int f_ = t_ ? si##b : si##a; int g_ = t_ ? si##a : si##b; si##a = f_; si##b = g_; }
    CSW(0,1) CSW(2,3) CSW(4,5) CSW(1,2) CSW(3,4)
    CSW(0,1) CSW(2,3) CSW(4,5) CSW(1,2) CSW(3,4)
    CSW(0,1) CSW(2,3) CSW(4,5) CSW(1,2) CSW(3,4)
#undef CSW
    float c1f = 0.f;
    #pragma unroll
    for (int k = 0; k < 8; ++k) c1f += psum[tid][k];
    const double C1 = (double)c1f * (double)invn[base + tid];  // Σ_all cos (incl self)
    // Z series (validated R4/R6-R9): Z ~= 1 + e^-1[(N-1) + (C1-1) + (N-1)/512]
    const double Nn = (double)n;
    const double Zval = 1.0 + exp(-1.0) * ((Nn - 1.0) + (C1 - 1.0) + (Nn - 1.0) / 512.0);
    const double mm = sv0;
    const double Zstar = Zval * exp(1.0 - mm);
    const double q0 = exp(sv0 - mm) / Zstar;
    const double q1 = exp(sv1 - mm) / Zstar;
    const double q2 = exp(sv2 - mm) / Zstar;
    const double e0 = exp(q0), e1 = exp(q1), e2 = exp(q2);  // second softmax on probs
    const double S = e0 + e1 + e2;
    wOut[tid][0] = (float)(e0 / S); iOut[tid][0] = si0;
    wOut[tid][1] = (float)(e1 / S); iOut[tid][1] = si1;
    wOut[tid][2] = (float)(e2 / S); iOut[tid][2] = si2;
  }
  __syncthreads();

  {  // gather + weighted sum: 16 threads/row x 16 floats
    const int r = tid >> 4, seg = tid & 15;
    const float w0 = wOut[r][0], w1 = wOut[r][1], w2 = wOut[r][2];
    const float* x0 = x + (size_t)iOut[r][0] * D;
    const float* x1 = x + (size_t)iOut[r][1] * D;
    const float* x2 = x + (size_t)iOut[r][2] * D;
    float* op = out + (size_t)(base + r) * D;
    #pragma unroll
    for (int d4 = 0; d4 < 4; ++d4) {
      const int d = seg * 16 + d4 * 4;
      float4 A = *reinterpret_cast<const float4*>(x0 + d);
      float4 B = *reinterpret_cast<const float4*>(x1 + d);
      float4 C = *reinterpret_cast<const float4*>(x2 + d);
      float4 o;
      o.x = w0 * A.x + w1 * B.x + w2 * C.x;
      o.y = w0 * A.y + w1 * B.y + w2 * C.y;
      o.z = w0 * A.z + w1 * B.z + w2 * C.z;
      o.w = w0 * A.w + w1 * B.w + w2 * C.w;
      *reinterpret_cast<float4*>(op + d) = o;
    }
  }
}

extern "C" void kernel_launch(void* const* d_in, const int* in_sizes, int n_in,
                              void* d_out, int out_size, void* d_ws, size_t ws_size,
                              hipStream_t stream) {
  const float* x = (const float*)d_in[0];
  const int n = in_sizes[0] / D;                        // 16384
  _Float16* xBs = (_Float16*)d_ws;                      // n*D fp16 swizzled (8 MB)
  double* fen64 = (double*)(xBs + (size_t)n * D);       // n fp64
  float*  invn  = (float*)(fen64 + n);                  // n fp32
  float*  g     = invn + n;                             // D fp32
  unsigned int* cand6 = (unsigned int*)(g + D);         // n*4*6 u32 (1.5 MB)
  float*  out   = (float*)d_out;

  (void)hipFuncSetAttribute((const void*)neighbors_kernel,
                            hipFuncAttributeMaxDynamicSharedMemorySize, 98304);

  hipLaunchKernelGGL(prep_kernel, dim3(n / 16), dim3(256), 0, stream,
                     x, fen64, invn, xBs, g, n);
  hipLaunchKernelGGL(gsum_kernel, dim3(n / 256), dim3(256), 0, stream, x, invn, g);
  hipLaunchKernelGGL(neighbors_kernel, dim3((n / BI) * 4), dim3(NTHR), 98304, stream,
                     xBs, cand6, n);
  hipLaunchKernelGGL(finalize_kernel, dim3(n / 32), dim3(512), 0, stream,
                     x, cand6, fen64, invn, g, out, n);
}

// Round 11
// 239.299 us; speedup vs baseline: 1.3405x; 1.3405x over previous
//
#include <hip/hip_runtime.h>
#include <math.h>

#define D      256
#define BI     128     // rows per block (8 m-tiles of 16; 4 mg-wave-groups x 2 tiles)
#define NTHR   1024    // 16 waves: mg = wv&3, jg = wv>>2
#define KL     3       // per-stream top-k
#define NC     6       // refine candidates per row per half
#define STILE  64      // j per supertile (4 tiles of 16) = 32 KB fp16
#define BUFH   16384   // halfs per stage buffer (32 KB); 3 buffers = 96 KB

typedef _Float16 half8 __attribute__((ext_vector_type(8)));
typedef float f32x4 __attribute__((ext_vector_type(4)));
typedef __attribute__((address_space(3))) unsigned int lds_u32;
typedef const __attribute__((address_space(1))) unsigned int glb_u32;

// s_waitcnt simm16 (gfx9/CDNA): vmcnt[3:0] | expcnt<<4 | lgkmcnt<<8 | vmcnt[5:4]<<14
#define WAITCNT_VM2  0xF72   // vmcnt(2)
#define WAITCNT_VM0  0xF70   // vmcnt(0)

#if __has_builtin(__builtin_amdgcn_sched_barrier)
#define SCHED_FENCE() __builtin_amdgcn_sched_barrier(0)
#else
#define SCHED_FENCE()
#endif

// ---- fused prep (R9-proven): per-row fp64 norm + invn + fp16 pack (tile order) ----
// pack layout: element [T*16+(l&15)][(l>>4)*8 + kc*32 + e] at halfs T*4096 + kc*512 + l*8
__global__ __launch_bounds__(256) void prep_kernel(const float* __restrict__ x,
    double* __restrict__ fen64, float* __restrict__ invn,
    _Float16* __restrict__ xBs, int n) {
  const int T   = blockIdx.x;          // one 16-row tile
  const int tid = threadIdx.x;
  const int r   = tid >> 4;
  const int t   = tid & 15;
  const int row = T * 16 + r;

  float4 v[4];
  const float* sp = x + (size_t)row * D + t * 16;
  #pragma unroll
  for (int q = 0; q < 4; ++q) v[q] = *reinterpret_cast<const float4*>(sp + q * 4);

  double s = 0.0;
  #pragma unroll
  for (int q = 0; q < 4; ++q)
    s += (double)v[q].x * v[q].x + (double)v[q].y * v[q].y +
         (double)v[q].z * v[q].z + (double)v[q].w * v[q].w;
  s += __shfl_down(s, 8); s += __shfl_down(s, 4);
  s += __shfl_down(s, 2); s += __shfl_down(s, 1);

  __shared__ float sInv[16];
  if (t == 0) {
    const double f = sqrt(s + D * 1e-6);   // ref adds 1e-6 per element before summing
    fen64[row] = f;
    const float iv = (float)(1.0 / f);
    invn[row] = iv;
    sInv[r] = iv;
  }
  __syncthreads();
  const float inv = sInv[r];

  const int kc  = t >> 1;
  const int hi0 = (t & 1) * 2;
  half8 h0, h1;
  h0[0] = (_Float16)(v[0].x * inv); h0[1] = (_Float16)(v[0].y * inv);
  h0[2] = (_Float16)(v[0].z * inv); h0[3] = (_Float16)(v[0].w * inv);
  h0[4] = (_Float16)(v[1].x * inv); h0[5] = (_Float16)(v[1].y * inv);
  h0[6] = (_Float16)(v[1].z * inv); h0[7] = (_Float16)(v[1].w * inv);
  h1[0] = (_Float16)(v[2].x * inv); h1[1] = (_Float16)(v[2].y * inv);
  h1[2] = (_Float16)(v[2].z * inv); h1[3] = (_Float16)(v[2].w * inv);
  h1[4] = (_Float16)(v[3].x * inv); h1[5] = (_Float16)(v[3].y * inv);
  h1[6] = (_Float16)(v[3].z * inv); h1[7] = (_Float16)(v[3].w * inv);
  _Float16* base = xBs + (size_t)T * 4096;
  *reinterpret_cast<half8*>(base + kc * 512 + (hi0 * 16 + r) * 8) = h0;
  *reinterpret_cast<half8*>(base + kc * 512 + ((hi0 + 1) * 16 + r) * 8) = h1;
}

__device__ inline void ins6(unsigned int v, unsigned int* b) {
  if (v > b[5]) {
    bool g0 = v > b[0], g1 = v > b[1], g2 = v > b[2], g3 = v > b[3], g4 = v > b[4];
    unsigned int o0 = b[0], o1 = b[1], o2 = b[2], o3 = b[3], o4 = b[4];
    b[5] = g4 ? o4 : v;             b[4] = g4 ? (g3 ? o3 : v) : o4;
    b[3] = g3 ? (g2 ? o2 : v) : o3; b[2] = g2 ? (g1 ? o1 : v) : o2;
    b[1] = g1 ? (g0 ? o0 : v) : o1; b[0] = g0 ? v : o0;
  }
}

// ---- main (byte-exact R8, proven 164 us): BI=128 x j-half; R6 pipeline ----
__global__ __launch_bounds__(NTHR, 4) void neighbors_kernel(
    const _Float16* __restrict__ xBs, unsigned int* __restrict__ cand6, int n) {
  extern __shared__ char smem[];
  _Float16* sB = (_Float16*)smem;                   // 3 x BUFH halfs (96 KB)
  unsigned int* cand = (unsigned int*)smem;         // [BI][192] aliases stage (96 KB)
  const int tid  = threadIdx.x;
  const int lane = tid & 63;
  const int wv   = tid >> 6;
  const int mg   = wv & 3;    // m-wave-group: 2 m-tiles of 16 (32 rows)
  const int jg   = wv >> 2;   // j-subtile (16 j) within 64-j supertile
  const int nIdx = lane & 15;
  const int quad = lane >> 4;
  const int ib   = blockIdx.x >> 1;
  const int h    = blockIdx.x & 1;      // j-half
  const int i0   = ib * BI;
  const int NST  = (n / 2) / STILE;     // 128 supertiles per half
  const int tb   = h * (n / 2 / 16);    // first j-tile index of this half

  // A fragments: 2 m-tiles x 8 k-chunks from swizzled xBs (layout == B-frags)
  half8 afrag[2][8];
  #pragma unroll
  for (int mt = 0; mt < 2; ++mt) {
    const _Float16* ap = xBs + (size_t)(i0 / 16 + 2 * mg + mt) * 4096 + lane * 8;
    #pragma unroll
    for (int kc = 0; kc < 8; ++kc)
      afrag[mt][kc] = *reinterpret_cast<const half8*>(ap + kc * 512);
  }

  unsigned int tk[8][KL];
  #pragma unroll
  for (int e = 0; e < 8; ++e)
    #pragma unroll
    for (int c = 0; c < KL; ++c) tk[e][c] = 0u;

  // DMA: supertile st = 4 contiguous tiles = 32 KB; wave copies its 2 KB (2 x 1 KB)
  auto dma_tile = [&](int st, int bufI) {
    const _Float16* src = xBs + ((size_t)tb + st * 4) * 4096 + wv * 1024 + lane * 8;
    _Float16* dst = sB + (size_t)bufI * BUFH + wv * 1024;
    #pragma unroll
    for (int c = 0; c < 2; ++c)
      __builtin_amdgcn_global_load_lds((glb_u32*)(src + c * 512),
                                       (lds_u32*)(dst + c * 512), 16, 0, 0);
  };

  auto compute = [&](int jt) {
    const int b = jt % 3;
    f32x4 acc0 = {-1.f, -1.f, -1.f, -1.f};   // acc = cos - 1 (<=0 except self)
    f32x4 acc1 = {-1.f, -1.f, -1.f, -1.f};
    const _Float16* bb = sB + (size_t)b * BUFH + jg * 4096 + lane * 8;
    #pragma unroll
    for (int kc = 0; kc < 8; ++kc) {
      const half8 bf = *reinterpret_cast<const half8*>(bb + kc * 512);
      acc0 = __builtin_amdgcn_mfma_f32_16x16x32_f16(afrag[0][kc], bf, acc0, 0, 0, 0);
      acc1 = __builtin_amdgcn_mfma_f32_16x16x32_f16(afrag[1][kc], bf, acc1, 0, 0, 0);
    }
    const int j = h * (n / 2) + jt * STILE + jg * 16 + nIdx;   // GLOBAL j
    const unsigned int jinv = 16383u - (unsigned int)j;
    #pragma unroll
    for (int mt = 0; mt < 2; ++mt) {
      #pragma unroll
      for (int r = 0; r < 4; ++r) {
        const float s = (mt == 0) ? acc0[r] : acc1[r];
        const int e = mt * 4 + r;
        // s<=0 for j!=i: ~bits monotone increasing; positive self maps above all.
        const unsigned int p = (~__float_as_uint(s) & 0xFFFFC000u) | jinv;
        if (p > tk[e][2]) {              // rare guarded insert (R8-proven lowest VALU)
          const bool g0 = p > tk[e][0], g1 = p > tk[e][1];
          const unsigned int o0 = tk[e][0], o1 = tk[e][1];
          tk[e][2] = g1 ? o1 : p;
          tk[e][1] = g0 ? o0 : (g1 ? p : o1);
          tk[e][0] = g0 ? p : o0;
        }
      }
    }
  };

  dma_tile(0, 0);
  dma_tile(1, 1);
  for (int jt = 0; jt < NST - 1; ++jt) {
    __builtin_amdgcn_s_waitcnt(WAITCNT_VM2);   // my 2 loads for buf jt landed
    __builtin_amdgcn_s_barrier();              // all waves' buf-jt loads landed
    SCHED_FENCE();
    if (jt + 2 < NST) dma_tile(jt + 2, (jt + 2) % 3);
    compute(jt);
  }
  __builtin_amdgcn_s_waitcnt(WAITCNT_VM0);
  __builtin_amdgcn_s_barrier();
  SCHED_FENCE();
  compute(NST - 1);

  __syncthreads();   // stage dead; switch to merge layout

  // deposit: row from verified 16x16 C/D mapping (col=lane&15, row=quad*4+reg)
  #pragma unroll
  for (int mt = 0; mt < 2; ++mt) {
    #pragma unroll
    for (int r = 0; r < 4; ++r) {
      const int row  = (2 * mg + mt) * 16 + quad * 4 + r;
      const int slot = jg * 16 + nIdx;
      #pragma unroll
      for (int c = 0; c < KL; ++c) cand[row * 192 + slot * KL + c] = tk[mt * 4 + r][c];
    }
  }
  __syncthreads();

  // stage-A: 8 threads/row reduce 24 candidates to top-6 in place
  {
    const int row = tid >> 3, seg = tid & 7, base = seg * 24;
    unsigned int best[NC];
    #pragma unroll
    for (int c = 0; c < NC; ++c) best[c] = 0u;
    for (int k = 0; k < 24; ++k) ins6(cand[row * 192 + base + k], best);
    #pragma unroll
    for (int c = 0; c < NC; ++c) cand[row * 192 + base + c] = best[c];
  }
  __syncthreads();

  // stage-B: one thread/row -> top-6 keys to global scratch [i][2][6]
  if (tid < BI) {
    unsigned int best[NC];
    #pragma unroll
    for (int c = 0; c < NC; ++c) best[c] = 0u;
    for (int seg = 0; seg < 8; ++seg)
      for (int c = 0; c < NC; ++c) ins6(cand[tid * 192 + seg * 24 + c], best);
    unsigned int* outp = cand6 + ((size_t)(i0 + tid) * 2 + h) * NC;
    #pragma unroll
    for (int c = 0; c < NC; ++c) outp[c] = best[c];
  }
}

// ---- finalize: merge halves, fp64 refine (2 thr/dot), constant-Z, weights, gather ----
// Z is per-row common-mode across q0..q2; second softmax cancels common-mode to
// first order (w-ratio err = eps*(qk-ql) ~ 8e-8), so Z = 1 + e^-1(N-1)(1+1/512).
__global__ __launch_bounds__(512) void finalize_kernel(
    const float* __restrict__ x, const unsigned int* __restrict__ cand6,
    const double* __restrict__ fen64, float* __restrict__ out, int n) {
  __shared__ int    sel[32][NC];
  __shared__ double s64[32][NC];
  __shared__ float  wOut[32][3];
  __shared__ int    iOut[32][3];
  const int tid = threadIdx.x;
  const int base = blockIdx.x * 32;

  if (tid < 32) {                       // merge 12 keys -> top-6
    const unsigned int* cp = cand6 + (size_t)(base + tid) * 12;
    unsigned int best[NC];
    #pragma unroll
    for (int c = 0; c < NC; ++c) best[c] = 0u;
    for (int k = 0; k < 12; ++k) ins6(cp[k], best);
    #pragma unroll
    for (int c = 0; c < NC; ++c) sel[tid][c] = 16383 - (int)(best[c] & 0x3FFFu);
  }
  __syncthreads();

  if (tid < 32 * NC * 2) {              // fp64 refine: 2 threads per dot, 128 d each
    const int r  = tid / (NC * 2);
    const int c2 = tid % (NC * 2);
    const int c  = c2 >> 1;
    const int hf = c2 & 1;
    const int j  = sel[r][c];
    const float* xi = x + (size_t)(base + r) * D + hf * 128;
    const float* xj = x + (size_t)j * D + hf * 128;
    double a0 = 0, a1 = 0, a2 = 0, a3 = 0;
    for (int d = 0; d < 128; d += 4) {
      float4 va = *reinterpret_cast<const float4*>(xi + d);
      float4 vb = *reinterpret_cast<const float4*>(xj + d);
      a0 += (double)va.x * vb.x; a1 += (double)va.y * vb.y;
      a2 += (double)va.z * vb.z; a3 += (double)va.w * vb.w;
    }
    double half_dot = (a0 + a1) + (a2 + a3);
    const double other = __shfl_xor(half_dot, 1);   // partner half (adjacent lane)
    if (hf == 0)
      s64[r][c] = (half_dot + other) / (fen64[base + r] * fen64[j]);
  }
  __syncthreads();

  if (tid < 32) {
    double sv0 = s64[tid][0], sv1 = s64[tid][1], sv2 = s64[tid][2],
           sv3 = s64[tid][3], sv4 = s64[tid][4], sv5 = s64[tid][5];
    int si0 = sel[tid][0], si1 = sel[tid][1], si2 = sel[tid][2],
        si3 = sel[tid][3], si4 = sel[tid][4], si5 = sel[tid][5];
#define CSW(a, b) { bool t_ = (sv##b > sv##a) || (sv##b == sv##a && si##b < si##a); \
    double d_ = t_ ? sv##b : sv##a; double e_ = t_ ? sv##a : sv##b; sv##a = d_; sv##b = e_; \
    int f_ = t_ ? si##b : si##a; int g_ = t_ ? si##a : si##b; si##a = f_; si##b = g_; }
    CSW(0,1) CSW(2,3) CSW(4,5) CSW(1,2) CSW(3,4)
    CSW(0,1) CSW(2,3) CSW(4,5) CSW(1,2) CSW(3,4)
    CSW(0,1) CSW(2,3) CSW(4,5) CSW(1,2) CSW(3,4)
#undef CSW
    const double Nn = (double)n;
    const double Zval = 1.0 + exp(-1.0) * (Nn - 1.0) * (1.0 + 1.0 / 512.0);
    const double mm = sv0;
    const double Zstar = Zval * exp(1.0 - mm);   // rebase from ref-max 1.0 to true max
    const double q0 = exp(sv0 - mm) / Zstar;
    const double q1 = exp(sv1 - mm) / Zstar;
    const double q2 = exp(sv2 - mm) / Zstar;
    const double e0 = exp(q0), e1 = exp(q1), e2 = exp(q2);  // second softmax on probs
    const double S = e0 + e1 + e2;
    wOut[tid][0] = (float)(e0 / S); iOut[tid][0] = si0;
    wOut[tid][1] = (float)(e1 / S); iOut[tid][1] = si1;
    wOut[tid][2] = (float)(e2 / S); iOut[tid][2] = si2;
  }
  __syncthreads();

  {  // gather + weighted sum: 16 threads/row x 16 floats
    const int r = tid >> 4, seg = tid & 15;
    const float w0 = wOut[r][0], w1 = wOut[r][1], w2 = wOut[r][2];
    const float* x0 = x + (size_t)iOut[r][0] * D;
    const float* x1 = x + (size_t)iOut[r][1] * D;
    const float* x2 = x + (size_t)iOut[r][2] * D;
    float* op = out + (size_t)(base + r) * D;
    #pragma unroll
    for (int d4 = 0; d4 < 4; ++d4) {
      const int d = seg * 16 + d4 * 4;
      float4 A = *reinterpret_cast<const float4*>(x0 + d);
      float4 B = *reinterpret_cast<const float4*>(x1 + d);
      float4 C = *reinterpret_cast<const float4*>(x2 + d);
      float4 o;
      o.x = w0 * A.x + w1 * B.x + w2 * C.x;
      o.y = w0 * A.y + w1 * B.y + w2 * C.y;
      o.z = w0 * A.z + w1 * B.z + w2 * C.z;
      o.w = w0 * A.w + w1 * B.w + w2 * C.w;
      *reinterpret_cast<float4*>(op + d) = o;
    }
  }
}

extern "C" void kernel_launch(void* const* d_in, const int* in_sizes, int n_in,
                              void* d_out, int out_size, void* d_ws, size_t ws_size,
                              hipStream_t stream) {
  const float* x = (const float*)d_in[0];
  const int n = in_sizes[0] / D;                        // 16384
  _Float16* xBs = (_Float16*)d_ws;                      // n*D fp16 swizzled (8 MB)
  double* fen64 = (double*)(xBs + (size_t)n * D);       // n fp64
  float*  invn  = (float*)(fen64 + n);                  // n fp32
  unsigned int* cand6 = (unsigned int*)(invn + n);      // n*2*6 u32 (768 KB)
  float*  out   = (float*)d_out;

  (void)hipFuncSetAttribute((const void*)neighbors_kernel,
                            hipFuncAttributeMaxDynamicSharedMemorySize, 98304);

  hipLaunchKernelGGL(prep_kernel, dim3(n / 16), dim3(256), 0, stream,
                     x, fen64, invn, xBs, n);
  hipLaunchKernelGGL(neighbors_kernel, dim3((n / BI) * 2), dim3(NTHR), 98304, stream,
                     xBs, cand6, n);
  hipLaunchKernelGGL(finalize_kernel, dim3(n / 32), dim3(512), 0, stream,
                     x, cand6, fen64, out, n);
}